// Round 7
// baseline (357.102 us; speedup 1.0000x reference)
//
#include <hip/hip_runtime.h>
#include <hip/hip_bf16.h>
#include <stdint.h>

using bf16 = __hip_bfloat16;
typedef __attribute__((ext_vector_type(8))) short short8;      // 8 bf16 MFMA frag
typedef __attribute__((ext_vector_type(4))) float f32x4;
typedef __attribute__((ext_vector_type(16))) float f32x16;
typedef __attribute__((ext_vector_type(4))) float float4v;
typedef __attribute__((ext_vector_type(4))) unsigned short us4;
typedef __attribute__((ext_vector_type(4))) uint32_t u32x4;

#define LDS_U32 __attribute__((address_space(3))) uint32_t
#define GLB_U32 __attribute__((address_space(1))) uint32_t

__device__ __forceinline__ unsigned short f2b(float f) {
  union { float f; uint32_t u; } x; x.f = f;
  uint32_t r = x.u + 0x7FFFu + ((x.u >> 16) & 1u);  // RNE
  return (unsigned short)(r >> 16);
}

__device__ __forceinline__ float max3f(float a, float b, float c) {
  float r;
  asm("v_max3_f32 %0, %1, %2, %3" : "=v"(r) : "v"(a), "v"(b), "v"(c));
  return r;
}

// ---------------- fp32 -> bf16 cast: q,k,v + 4 weights in one launch ----------------
__global__ void cast_all(const float* __restrict__ q, const float* __restrict__ k,
                         const float* __restrict__ v, const float* __restrict__ Wq,
                         const float* __restrict__ Wk, const float* __restrict__ Wv,
                         const float* __restrict__ Wo,
                         bf16* __restrict__ qb, bf16* __restrict__ kb,
                         bf16* __restrict__ vb, bf16* __restrict__ Wqb,
                         bf16* __restrict__ Wkb, bf16* __restrict__ Wvb,
                         bf16* __restrict__ Wob) {
  const int NQ = 1 << 20;   // float4 vecs per q/k/v
  const int NW = 1 << 18;   // float4 vecs per weight
  const int total = 3 * NQ + 4 * NW;
  for (int i = blockIdx.x * blockDim.x + threadIdx.x; i < total;
       i += gridDim.x * blockDim.x) {
    const float* s; bf16* d; int vi;
    if (i < 3 * NQ) {
      int a = i >> 20; vi = i & (NQ - 1);
      s = (a == 0) ? q : (a == 1) ? k : v;
      d = (a == 0) ? qb : (a == 1) ? kb : vb;
    } else {
      int j = i - 3 * NQ;
      int a = j >> 18; vi = j & (NW - 1);
      s = (a == 0) ? Wq : (a == 1) ? Wk : (a == 2) ? Wv : Wo;
      d = (a == 0) ? Wqb : (a == 1) ? Wkb : (a == 2) ? Wvb : Wob;
    }
    float4v x = ((const float4v*)s)[vi];
    us4 y;
    y.x = f2b(x.x); y.y = f2b(x.y); y.z = f2b(x.z); y.w = f2b(x.w);
    ((us4*)d)[vi] = y;
  }
}

// ---------------- fused QKV projection: 128x128 tiles, bf16 gload_lds ----------------
__global__ __launch_bounds__(256, 2)
void qkv_proj(const bf16* __restrict__ Aq, const bf16* __restrict__ Ak,
              const bf16* __restrict__ Av,
              const bf16* __restrict__ Wq, const bf16* __restrict__ Wk,
              const bf16* __restrict__ Wv,
              bf16* __restrict__ Qh, bf16* __restrict__ KF, bf16* __restrict__ VF) {
  __shared__ bf16 Alds[128 * 64];
  __shared__ bf16 Blds[128 * 64];
  const int t = threadIdx.x, lane = t & 63, wave = t >> 6;
  const int l15 = lane & 15, l4 = lane >> 4;
  const int p = blockIdx.x;
  const int l = (p & 7) * 96 + (p >> 3);       // contiguous 96-block chunk per XCD
  const int grp = l >> 3;                       // seg*32 + m
  const int n0 = (l & 7) * 128;
  const int seg = grp >> 5;
  const int m0 = (grp & 31) * 128;
  const bf16* A = (seg == 0) ? Aq : (seg == 1) ? Ak : Av;
  const bf16* B = (seg == 0) ? Wq : (seg == 1) ? Wk : Wv;
  const int K = 1024;
  const int wr = (wave >> 1) * 64, wc = (wave & 1) * 64;
  const float SCLE = 0.18033688011112042f;  // (1/sqrt(64))*log2(e), folded into Q

  f32x4 acc[4][4] = {};

  for (int kt = 0; kt < K; kt += 64) {
#pragma unroll
    for (int i = 0; i < 4; ++i) {
      int f = i * 256 + t, row = f >> 3, csrc = (f & 7) ^ (row & 7);
      __builtin_amdgcn_global_load_lds(
          (const GLB_U32*)(A + (size_t)(m0 + row) * K + kt + csrc * 8),
          (LDS_U32*)(Alds + f * 8), 16, 0, 0);
      __builtin_amdgcn_global_load_lds(
          (const GLB_U32*)(B + (size_t)(n0 + row) * K + kt + csrc * 8),
          (LDS_U32*)(Blds + f * 8), 16, 0, 0);
    }
    __syncthreads();
#pragma unroll
    for (int ks = 0; ks < 2; ++ks) {
      short8 af[4], bfr[4];
#pragma unroll
      for (int mi = 0; mi < 4; ++mi) {
        int row = wr + mi * 16 + l15;
        int ch = (ks * 4 + l4) ^ (row & 7);
        af[mi] = *(const short8*)(Alds + row * 64 + ch * 8);
      }
#pragma unroll
      for (int ni = 0; ni < 4; ++ni) {
        int row = wc + ni * 16 + l15;
        int ch = (ks * 4 + l4) ^ (row & 7);
        bfr[ni] = *(const short8*)(Blds + row * 64 + ch * 8);
      }
#pragma unroll
      for (int mi = 0; mi < 4; ++mi)
#pragma unroll
        for (int ni = 0; ni < 4; ++ni)
          acc[mi][ni] = __builtin_amdgcn_mfma_f32_16x16x32_bf16(
              af[mi], bfr[ni], acc[mi][ni], 0, 0, 0);
    }
    __syncthreads();
  }

#pragma unroll
  for (int mi = 0; mi < 4; ++mi) {
#pragma unroll
    for (int ni = 0; ni < 4; ++ni) {
      int rbase = m0 + wr + mi * 16 + l4 * 4;
      int col = n0 + wc + ni * 16 + l15;
      if (seg == 0) {
        unsigned short* C = (unsigned short*)Qh;
#pragma unroll
        for (int r = 0; r < 4; ++r)
          C[(size_t)(rbase + r) * 1024 + col] = f2b(acc[mi][ni][r] * SCLE);
      } else if (seg == 1) {
        // KF[bh][s>>5][d>>4][(d>>3)&1][s&31][d&7]
        unsigned short* C = (unsigned short*)KF;
        int h = col >> 6, d = col & 63;
#pragma unroll
        for (int r = 0; r < 4; ++r) {
          int row = rbase + r;
          int b = row >> 11, s = row & 2047;
          size_t idx = (size_t)(b * 16 + h) * 131072 +
                       ((((s >> 5) * 4 + (d >> 4)) * 2 + ((d >> 3) & 1)) * 256) +
                       (s & 31) * 8 + (d & 7);
          C[idx] = f2b(acc[mi][ni][r]);
        }
      } else {
        // VF[bh][s>>6][(d>>5)&1][(s>>4)&3][(s>>3)&1][d&31][s&7]; 4 consec s -> us4
        unsigned short* C = (unsigned short*)VF;
        int h = col >> 6, d = col & 63;
        int row = rbase;
        int b = row >> 11, s = row & 2047;
        size_t idx = (size_t)(b * 16 + h) * 131072 +
                     (((((s >> 6) * 2 + ((d >> 5) & 1)) * 4 + ((s >> 4) & 3)) * 2 +
                       ((s >> 3) & 1)) * 256) +
                     (d & 31) * 8 + (s & 7);
        us4 y;
        y.x = f2b(acc[mi][ni][0]); y.y = f2b(acc[mi][ni][1]);
        y.z = f2b(acc[mi][ni][2]); y.w = f2b(acc[mi][ni][3]);
        *(us4*)(C + idx) = y;
      }
    }
  }
}

// ---------------- output projection: 128x64 tiles, bf16 gload_lds both, XCD-chunked --
__global__ __launch_bounds__(256, 2)
void gemm_o(const bf16* __restrict__ A, const bf16* __restrict__ B,
            float* __restrict__ C) {
  __shared__ bf16 Alds[128 * 64];
  __shared__ bf16 Blds[64 * 64];
  const int t = threadIdx.x, lane = t & 63, wave = t >> 6;
  const int l15 = lane & 15, l4 = lane >> 4;
  const int p = blockIdx.x;
  const int l = (p & 7) * 64 + (p >> 3);       // 64-block chunk per XCD
  const int m0 = (l >> 4) * 128;
  const int n0 = (l & 15) * 64;
  const int K = 1024;
  const int wr = (wave >> 1) * 64, wc = (wave & 1) * 32;

  f32x4 acc[4][2] = {};

  for (int kt = 0; kt < K; kt += 64) {
#pragma unroll
    for (int i = 0; i < 4; ++i) {
      int f = i * 256 + t, row = f >> 3, csrc = (f & 7) ^ (row & 7);
      __builtin_amdgcn_global_load_lds(
          (const GLB_U32*)(A + (size_t)(m0 + row) * K + kt + csrc * 8),
          (LDS_U32*)(Alds + f * 8), 16, 0, 0);
    }
#pragma unroll
    for (int i = 0; i < 2; ++i) {
      int f = i * 256 + t, row = f >> 3, csrc = (f & 7) ^ (row & 7);
      __builtin_amdgcn_global_load_lds(
          (const GLB_U32*)(B + (size_t)(n0 + row) * K + kt + csrc * 8),
          (LDS_U32*)(Blds + f * 8), 16, 0, 0);
    }
    __syncthreads();
#pragma unroll
    for (int ks = 0; ks < 2; ++ks) {
      short8 af[4], bfr[2];
#pragma unroll
      for (int mi = 0; mi < 4; ++mi) {
        int row = wr + mi * 16 + l15;
        int ch = (ks * 4 + l4) ^ (row & 7);
        af[mi] = *(const short8*)(Alds + row * 64 + ch * 8);
      }
#pragma unroll
      for (int ni = 0; ni < 2; ++ni) {
        int row = wc + ni * 16 + l15;
        int ch = (ks * 4 + l4) ^ (row & 7);
        bfr[ni] = *(const short8*)(Blds + row * 64 + ch * 8);
      }
#pragma unroll
      for (int mi = 0; mi < 4; ++mi)
#pragma unroll
        for (int ni = 0; ni < 2; ++ni)
          acc[mi][ni] = __builtin_amdgcn_mfma_f32_16x16x32_bf16(
              af[mi], bfr[ni], acc[mi][ni], 0, 0, 0);
    }
    __syncthreads();
  }

#pragma unroll
  for (int mi = 0; mi < 4; ++mi)
#pragma unroll
    for (int ni = 0; ni < 2; ++ni) {
      int rbase = m0 + wr + mi * 16 + l4 * 4;
      int col = n0 + wc + ni * 16 + l15;
#pragma unroll
      for (int r = 0; r < 4; ++r)
        C[(size_t)(rbase + r) * 1024 + col] = acc[mi][ni][r];
    }
}

// ---------------- causal flash attention: 4-way split-K, frag-major K/V ----------
// 1024 blocks: (bh, job). 4 waves = 4 k-quarters of strips {job, 63-job}.
// 4-way merge via LDS. All waves ~8.4 tiles -> balanced; 4 waves/SIMD occupancy.
__global__ __launch_bounds__(256, 4)
void attn_fwd(const bf16* __restrict__ Q, const bf16* __restrict__ KF,
              const bf16* __restrict__ VF, const int* __restrict__ mask,
              bf16* __restrict__ O) {
  const int lin = blockIdx.x;
  const int xcd = lin & 7, rest = lin >> 3;
  const int bh = xcd + 8 * (rest & 3);           // 4 heads per XCD -> K/V L2-resident
  const int job = rest >> 2;                     // 0..31
  const int b = bh >> 4, h = bh & 15;
  const int wq = threadIdx.x >> 6, lane = threadIdx.x & 63;
  const int l31 = lane & 31, hi = lane >> 5;

  __shared__ float accL[3][64][33];
  __shared__ float mlL[3][64][2];

  const size_t bqk = (size_t)b * 2048 * 1024 + h * 64;
  const size_t fbase = (size_t)bh * 131072;  // KF/VF per-head base

  for (int si = 0; si < 2; ++si) {
    const int s = si ? (63 - job) : job;   // strip: 32 q-rows
    const int q0 = 32 * s;
    const int T = (s >> 1) + 1;
    const int tstart = (T * wq) >> 2;
    const int tend = (T * (wq + 1)) >> 2;

    short8 qf[4];
#pragma unroll
    for (int s4 = 0; s4 < 4; ++s4)
      qf[s4] = *(const short8*)(Q + bqk + (size_t)(q0 + l31) * 1024 + 16 * s4 + 8 * hi);

    // once-per-range pad-mask scan (all-ones fast path)
    int anyz = 0;
    for (int i = tstart * 64 + lane; i < tend * 64; i += 64)
      anyz |= (mask[b * 2048 + i] == 0);
    const bool doMask = __any(anyz);

    f32x16 acc0 = {}, acc1 = {};
    float m = -1e30f, l = 0.f;

    short8 kf[2][4], kn[2][4], vf[2][4];
    if (tstart < tend) {
#pragma unroll
      for (int u = 0; u < 2; ++u)
#pragma unroll
        for (int s4 = 0; s4 < 4; ++s4)
          kf[u][s4] = *(const short8*)(KF + fbase +
              ((size_t)((2 * tstart + u) * 4 + s4) * 2 + hi) * 256 + l31 * 8);
    }

    for (int tt = tstart; tt < tend; ++tt) {
#pragma unroll
      for (int n = 0; n < 2; ++n)
#pragma unroll
        for (int tq = 0; tq < 4; ++tq)
          vf[n][tq] = *(const short8*)(VF + fbase +
              ((size_t)(((tt * 2 + n) * 4 + tq) * 2 + hi)) * 256 + l31 * 8);

      f32x16 s0 = {}, s1 = {};
      __builtin_amdgcn_s_setprio(1);
#pragma unroll
      for (int s4 = 0; s4 < 4; ++s4) {
        s0 = __builtin_amdgcn_mfma_f32_32x32x16_bf16(kf[0][s4], qf[s4], s0, 0, 0, 0);
        s1 = __builtin_amdgcn_mfma_f32_32x32x16_bf16(kf[1][s4], qf[s4], s1, 0, 0, 0);
      }
      __builtin_amdgcn_s_setprio(0);
      if (tt + 1 < tend) {  // K prefetch for next tile
#pragma unroll
        for (int u = 0; u < 2; ++u)
#pragma unroll
          for (int s4 = 0; s4 < 4; ++s4)
            kn[u][s4] = *(const short8*)(KF + fbase +
                ((size_t)((2 * (tt + 1) + u) * 4 + s4) * 2 + hi) * 256 + l31 * 8);
      }

      float w[2][16];
#pragma unroll
      for (int p = 0; p < 16; ++p) { w[0][p] = s0[p]; w[1][p] = s1[p]; }

      if (doMask) {  // pad-mask path (wave-uniform branch)
        int mv = mask[b * 2048 + tt * 64 + lane];
        uint64_t bits = __ballot(mv != 0);
        uint64_t bs = bits >> (4 * hi);
#pragma unroll
        for (int u = 0; u < 2; ++u)
#pragma unroll
          for (int p = 0; p < 16; ++p)
            if (!((bs >> (32 * u + (p & 3) + 8 * (p >> 2))) & 1)) w[u][p] = -3e38f;
      }
      if (tt == T - 1) {  // causal clamp, diagonal tile only (last quarter's last tile)
        int qr = 32 * (s & 1) + l31 - 4 * hi;
#pragma unroll
        for (int u = 0; u < 2; ++u)
#pragma unroll
          for (int p = 0; p < 16; ++p)
            if (32 * u + (p & 3) + 8 * (p >> 2) > qr) w[u][p] = -3e38f;
      }

      // tile max: v_max3 chain (16 ops) + one cross-half swap
      float tm = max3f(w[0][0], w[0][1], w[0][2]);
#pragma unroll
      for (int p = 3; p + 1 < 16; p += 2) tm = max3f(tm, w[0][p], w[0][p + 1]);
      tm = max3f(tm, w[0][15], w[1][0]);
#pragma unroll
      for (int p = 1; p + 1 < 16; p += 2) tm = max3f(tm, w[1][p], w[1][p + 1]);
      tm = fmaxf(tm, w[1][15]);
      tm = fmaxf(tm, __shfl_xor(tm, 32));

      // defer-max (T13)
      if (!__all(tm <= m + 8.f)) {
        float mn = fmaxf(m, tm);
        float corr = __builtin_amdgcn_exp2f(m - mn);
        m = mn; l *= corr;
#pragma unroll
        for (int p = 0; p < 16; ++p) {
          float ct = __shfl(corr, (p & 3) + 8 * (p >> 2) + 4 * hi);
          acc0[p] *= ct; acc1[p] *= ct;
        }
      }

      float ts = 0.f;
#pragma unroll
      for (int u = 0; u < 2; ++u)
#pragma unroll
        for (int p = 0; p < 16; ++p) {
          float pv = __builtin_amdgcn_exp2f(w[u][p] - m);
          w[u][p] = pv; ts += pv;
        }
      ts += __shfl_xor(ts, 32);
      l += ts;

      // pack P to bf16 pairs (T12)
      uint32_t pkk[2][8];
#pragma unroll
      for (int u = 0; u < 2; ++u)
#pragma unroll
        for (int a = 0; a < 4; ++a)
#pragma unroll
          for (int w2 = 0; w2 < 2; ++w2) {
            uint32_t r;
            asm("v_cvt_pk_bf16_f32 %0, %1, %2"
                : "=v"(r) : "v"(w[u][4 * a + 2 * w2]), "v"(w[u][4 * a + 2 * w2 + 1]));
            pkk[u][2 * a + w2] = r;
          }

      // PV A-frags via permlane32_swap, then 8 PV MFMAs
#pragma unroll
      for (int tq = 0; tq < 4; ++tq) {
        const int u = tq >> 1, alo = 2 * (tq & 1);
        uint32_t a0 = pkk[u][2 * alo + 0], b0 = pkk[u][2 * alo + 2];
        uint32_t a1 = pkk[u][2 * alo + 1], b1 = pkk[u][2 * alo + 3];
        asm("v_permlane32_swap_b32 %0, %1" : "+v"(a0), "+v"(b0));
        asm("v_permlane32_swap_b32 %0, %1" : "+v"(a1), "+v"(b1));
        u32x4 wv = {a0, a1, b0, b1};
        short8 paf = __builtin_bit_cast(short8, wv);
        __builtin_amdgcn_s_setprio(1);
        acc0 = __builtin_amdgcn_mfma_f32_32x32x16_bf16(paf, vf[0][tq], acc0, 0, 0, 0);
        acc1 = __builtin_amdgcn_mfma_f32_32x32x16_bf16(paf, vf[1][tq], acc1, 0, 0, 0);
        __builtin_amdgcn_s_setprio(0);
      }

#pragma unroll
      for (int u = 0; u < 2; ++u)
#pragma unroll
        for (int s4 = 0; s4 < 4; ++s4) kf[u][s4] = kn[u][s4];
    }

    // ---- 4-way split-K merge: waves 1..3 publish, wave 0 combines + writes ----
    if (wq) {
#pragma unroll
      for (int p = 0; p < 16; ++p) {
        accL[wq - 1][lane][p] = acc0[p];
        accL[wq - 1][lane][16 + p] = acc1[p];
      }
      mlL[wq - 1][lane][0] = m; mlL[wq - 1][lane][1] = l;
    }
    __syncthreads();
    if (wq == 0) {
      float ms = m;
#pragma unroll
      for (int j = 0; j < 3; ++j) ms = fmaxf(ms, mlL[j][lane][0]);
      float f0 = __builtin_amdgcn_exp2f(m - ms);
      float lsum = f0 * l;
      float fj[3];
#pragma unroll
      for (int j = 0; j < 3; ++j) {
        fj[j] = __builtin_amdgcn_exp2f(mlL[j][lane][0] - ms);
        lsum += fj[j] * mlL[j][lane][1];
      }
      float inv = 1.f / lsum;
      f0 *= inv;
#pragma unroll
      for (int j = 0; j < 3; ++j) fj[j] *= inv;
      unsigned short* Ou = (unsigned short*)O;
#pragma unroll
      for (int p = 0; p < 16; ++p) {
        int crow = (p & 3) + 8 * (p >> 2) + 4 * hi;
        float w0 = __shfl(f0, crow);
        float o0 = acc0[p] * w0, o1 = acc1[p] * w0;
#pragma unroll
        for (int j = 0; j < 3; ++j) {
          float wj = __shfl(fj[j], crow);
          o0 += accL[j][lane][p] * wj;
          o1 += accL[j][lane][16 + p] * wj;
        }
        size_t ro = (size_t)(b * 2048 + q0 + crow) * 1024 + h * 64;
        Ou[ro + l31] = f2b(o0);
        Ou[ro + 32 + l31] = f2b(o1);
      }
    }
    __syncthreads();
  }
}

// ---------------- launch ----------------
extern "C" void kernel_launch(void* const* d_in, const int* in_sizes, int n_in,
                              void* d_out, int out_size, void* d_ws, size_t ws_size,
                              hipStream_t stream) {
  const float* q = (const float*)d_in[0];
  const float* k = (const float*)d_in[1];
  const float* v = (const float*)d_in[2];
  const int* mask = (const int*)d_in[3];
  const float* Wq = (const float*)d_in[4];
  const float* Wk = (const float*)d_in[5];
  const float* Wv = (const float*)d_in[6];
  const float* Wo = (const float*)d_in[7];
  float* out = (float*)d_out;

  const size_t NT = 4096 * 1024;
  const size_t NW = 1024 * 1024;
  bf16* p = (bf16*)d_ws;
  bf16* qb = p;  p += NT;
  bf16* kb = p;  p += NT;
  bf16* vb = p;  p += NT;
  bf16* Wqb = p; p += NW;
  bf16* Wkb = p; p += NW;
  bf16* Wvb = p; p += NW;
  bf16* Wob = p; p += NW;
  bf16* Qh = p;  p += NT;
  bf16* KF = p;  p += NT;
  bf16* VF = p;  p += NT;
  bf16* Oh = p;  p += NT;

  cast_all<<<2048, 256, 0, stream>>>(q, k, v, Wq, Wk, Wv, Wo,
                                     qb, kb, vb, Wqb, Wkb, Wvb, Wob);
  qkv_proj<<<768, 256, 0, stream>>>(qb, kb, vb, Wqb, Wkb, Wvb, Qh, KF, VF);
  attn_fwd<<<1024, 256, 0, stream>>>(Qh, KF, VF, mask, Oh);
  gemm_o<<<512, 256, 0, stream>>>(Oh, Wob, out);
}

// Round 8
// 197.429 us; speedup vs baseline: 1.8088x; 1.8088x over previous
//
#include <hip/hip_runtime.h>
#include <hip/hip_bf16.h>
#include <stdint.h>

using bf16 = __hip_bfloat16;
typedef __attribute__((ext_vector_type(8))) short short8;      // 8 bf16 MFMA frag
typedef __attribute__((ext_vector_type(4))) float f32x4;
typedef __attribute__((ext_vector_type(16))) float f32x16;
typedef __attribute__((ext_vector_type(4))) float float4v;
typedef __attribute__((ext_vector_type(4))) unsigned short us4;
typedef __attribute__((ext_vector_type(4))) uint32_t u32x4;

#define LDS_U32 __attribute__((address_space(3))) uint32_t
#define GLB_U32 __attribute__((address_space(1))) uint32_t

__device__ __forceinline__ unsigned short f2b(float f) {
  union { float f; uint32_t u; } x; x.f = f;
  uint32_t r = x.u + 0x7FFFu + ((x.u >> 16) & 1u);  // RNE
  return (unsigned short)(r >> 16);
}

__device__ __forceinline__ float max3f(float a, float b, float c) {
  float r;
  asm("v_max3_f32 %0, %1, %2, %3" : "=v"(r) : "v"(a), "v"(b), "v"(c));
  return r;
}

// ---------------- fp32 -> bf16 cast: q,k,v + 4 weights in one launch ----------------
__global__ void cast_all(const float* __restrict__ q, const float* __restrict__ k,
                         const float* __restrict__ v, const float* __restrict__ Wq,
                         const float* __restrict__ Wk, const float* __restrict__ Wv,
                         const float* __restrict__ Wo,
                         bf16* __restrict__ qb, bf16* __restrict__ kb,
                         bf16* __restrict__ vb, bf16* __restrict__ Wqb,
                         bf16* __restrict__ Wkb, bf16* __restrict__ Wvb,
                         bf16* __restrict__ Wob) {
  const int NQ = 1 << 20;   // float4 vecs per q/k/v
  const int NW = 1 << 18;   // float4 vecs per weight
  const int total = 3 * NQ + 4 * NW;
  for (int i = blockIdx.x * blockDim.x + threadIdx.x; i < total;
       i += gridDim.x * blockDim.x) {
    const float* s; bf16* d; int vi;
    if (i < 3 * NQ) {
      int a = i >> 20; vi = i & (NQ - 1);
      s = (a == 0) ? q : (a == 1) ? k : v;
      d = (a == 0) ? qb : (a == 1) ? kb : vb;
    } else {
      int j = i - 3 * NQ;
      int a = j >> 18; vi = j & (NW - 1);
      s = (a == 0) ? Wq : (a == 1) ? Wk : (a == 2) ? Wv : Wo;
      d = (a == 0) ? Wqb : (a == 1) ? Wkb : (a == 2) ? Wvb : Wob;
    }
    float4v x = ((const float4v*)s)[vi];
    us4 y;
    y.x = f2b(x.x); y.y = f2b(x.y); y.z = f2b(x.z); y.w = f2b(x.w);
    ((us4*)d)[vi] = y;
  }
}

// ---------------- fused QKV projection: 128x128 tiles, bf16 gload_lds ----------------
__global__ __launch_bounds__(256, 2)
void qkv_proj(const bf16* __restrict__ Aq, const bf16* __restrict__ Ak,
              const bf16* __restrict__ Av,
              const bf16* __restrict__ Wq, const bf16* __restrict__ Wk,
              const bf16* __restrict__ Wv,
              bf16* __restrict__ Qh, bf16* __restrict__ KF, bf16* __restrict__ VF) {
  __shared__ bf16 Alds[128 * 64];
  __shared__ bf16 Blds[128 * 64];
  const int t = threadIdx.x, lane = t & 63, wave = t >> 6;
  const int l15 = lane & 15, l4 = lane >> 4;
  const int p = blockIdx.x;
  const int l = (p & 7) * 96 + (p >> 3);       // contiguous 96-block chunk per XCD
  const int grp = l >> 3;                       // seg*32 + m
  const int n0 = (l & 7) * 128;
  const int seg = grp >> 5;
  const int m0 = (grp & 31) * 128;
  const bf16* A = (seg == 0) ? Aq : (seg == 1) ? Ak : Av;
  const bf16* B = (seg == 0) ? Wq : (seg == 1) ? Wk : Wv;
  const int K = 1024;
  const int wr = (wave >> 1) * 64, wc = (wave & 1) * 64;
  const float SCLE = 0.18033688011112042f;  // (1/sqrt(64))*log2(e), folded into Q

  f32x4 acc[4][4] = {};

  for (int kt = 0; kt < K; kt += 64) {
#pragma unroll
    for (int i = 0; i < 4; ++i) {
      int f = i * 256 + t, row = f >> 3, csrc = (f & 7) ^ (row & 7);
      __builtin_amdgcn_global_load_lds(
          (const GLB_U32*)(A + (size_t)(m0 + row) * K + kt + csrc * 8),
          (LDS_U32*)(Alds + f * 8), 16, 0, 0);
      __builtin_amdgcn_global_load_lds(
          (const GLB_U32*)(B + (size_t)(n0 + row) * K + kt + csrc * 8),
          (LDS_U32*)(Blds + f * 8), 16, 0, 0);
    }
    __syncthreads();
#pragma unroll
    for (int ks = 0; ks < 2; ++ks) {
      short8 af[4], bfr[4];
#pragma unroll
      for (int mi = 0; mi < 4; ++mi) {
        int row = wr + mi * 16 + l15;
        int ch = (ks * 4 + l4) ^ (row & 7);
        af[mi] = *(const short8*)(Alds + row * 64 + ch * 8);
      }
#pragma unroll
      for (int ni = 0; ni < 4; ++ni) {
        int row = wc + ni * 16 + l15;
        int ch = (ks * 4 + l4) ^ (row & 7);
        bfr[ni] = *(const short8*)(Blds + row * 64 + ch * 8);
      }
#pragma unroll
      for (int mi = 0; mi < 4; ++mi)
#pragma unroll
        for (int ni = 0; ni < 4; ++ni)
          acc[mi][ni] = __builtin_amdgcn_mfma_f32_16x16x32_bf16(
              af[mi], bfr[ni], acc[mi][ni], 0, 0, 0);
    }
    __syncthreads();
  }

#pragma unroll
  for (int mi = 0; mi < 4; ++mi) {
#pragma unroll
    for (int ni = 0; ni < 4; ++ni) {
      int rbase = m0 + wr + mi * 16 + l4 * 4;
      int col = n0 + wc + ni * 16 + l15;
      if (seg == 0) {
        unsigned short* C = (unsigned short*)Qh;
#pragma unroll
        for (int r = 0; r < 4; ++r)
          C[(size_t)(rbase + r) * 1024 + col] = f2b(acc[mi][ni][r] * SCLE);
      } else if (seg == 1) {
        // KF[bh][s>>5][d>>4][(d>>3)&1][s&31][d&7]
        unsigned short* C = (unsigned short*)KF;
        int h = col >> 6, d = col & 63;
#pragma unroll
        for (int r = 0; r < 4; ++r) {
          int row = rbase + r;
          int b = row >> 11, s = row & 2047;
          size_t idx = (size_t)(b * 16 + h) * 131072 +
                       ((((s >> 5) * 4 + (d >> 4)) * 2 + ((d >> 3) & 1)) * 256) +
                       (s & 31) * 8 + (d & 7);
          C[idx] = f2b(acc[mi][ni][r]);
        }
      } else {
        // VF[bh][s>>6][(d>>5)&1][(s>>4)&3][(s>>3)&1][d&31][s&7]; 4 consec s -> us4
        unsigned short* C = (unsigned short*)VF;
        int h = col >> 6, d = col & 63;
        int row = rbase;
        int b = row >> 11, s = row & 2047;
        size_t idx = (size_t)(b * 16 + h) * 131072 +
                     (((((s >> 6) * 2 + ((d >> 5) & 1)) * 4 + ((s >> 4) & 3)) * 2 +
                       ((s >> 3) & 1)) * 256) +
                     (d & 31) * 8 + (s & 7);
        us4 y;
        y.x = f2b(acc[mi][ni][0]); y.y = f2b(acc[mi][ni][1]);
        y.z = f2b(acc[mi][ni][2]); y.w = f2b(acc[mi][ni][3]);
        *(us4*)(C + idx) = y;
      }
    }
  }
}

// ---------------- output projection: 128x64 tiles, bf16 gload_lds both, XCD-chunked --
__global__ __launch_bounds__(256, 2)
void gemm_o(const bf16* __restrict__ A, const bf16* __restrict__ B,
            float* __restrict__ C) {
  __shared__ bf16 Alds[128 * 64];
  __shared__ bf16 Blds[64 * 64];
  const int t = threadIdx.x, lane = t & 63, wave = t >> 6;
  const int l15 = lane & 15, l4 = lane >> 4;
  const int p = blockIdx.x;
  const int l = (p & 7) * 64 + (p >> 3);       // 64-block chunk per XCD
  const int m0 = (l >> 4) * 128;
  const int n0 = (l & 15) * 64;
  const int K = 1024;
  const int wr = (wave >> 1) * 64, wc = (wave & 1) * 32;

  f32x4 acc[4][2] = {};

  for (int kt = 0; kt < K; kt += 64) {
#pragma unroll
    for (int i = 0; i < 4; ++i) {
      int f = i * 256 + t, row = f >> 3, csrc = (f & 7) ^ (row & 7);
      __builtin_amdgcn_global_load_lds(
          (const GLB_U32*)(A + (size_t)(m0 + row) * K + kt + csrc * 8),
          (LDS_U32*)(Alds + f * 8), 16, 0, 0);
    }
#pragma unroll
    for (int i = 0; i < 2; ++i) {
      int f = i * 256 + t, row = f >> 3, csrc = (f & 7) ^ (row & 7);
      __builtin_amdgcn_global_load_lds(
          (const GLB_U32*)(B + (size_t)(n0 + row) * K + kt + csrc * 8),
          (LDS_U32*)(Blds + f * 8), 16, 0, 0);
    }
    __syncthreads();
#pragma unroll
    for (int ks = 0; ks < 2; ++ks) {
      short8 af[4], bfr[2];
#pragma unroll
      for (int mi = 0; mi < 4; ++mi) {
        int row = wr + mi * 16 + l15;
        int ch = (ks * 4 + l4) ^ (row & 7);
        af[mi] = *(const short8*)(Alds + row * 64 + ch * 8);
      }
#pragma unroll
      for (int ni = 0; ni < 2; ++ni) {
        int row = wc + ni * 16 + l15;
        int ch = (ks * 4 + l4) ^ (row & 7);
        bfr[ni] = *(const short8*)(Blds + row * 64 + ch * 8);
      }
#pragma unroll
      for (int mi = 0; mi < 4; ++mi)
#pragma unroll
        for (int ni = 0; ni < 2; ++ni)
          acc[mi][ni] = __builtin_amdgcn_mfma_f32_16x16x32_bf16(
              af[mi], bfr[ni], acc[mi][ni], 0, 0, 0);
    }
    __syncthreads();
  }

#pragma unroll
  for (int mi = 0; mi < 4; ++mi)
#pragma unroll
    for (int ni = 0; ni < 2; ++ni) {
      int rbase = m0 + wr + mi * 16 + l4 * 4;
      int col = n0 + wc + ni * 16 + l15;
#pragma unroll
      for (int r = 0; r < 4; ++r)
        C[(size_t)(rbase + r) * 1024 + col] = acc[mi][ni][r];
    }
}

// ---------------- causal flash attention: 4-way split-K, frag-major K/V ----------
// 1024 blocks: (bh, job). 4 waves = 4 k-quarters of strips {job, 63-job}.
// 4-way merge via LDS. VGPR must stay <=128 for 4 waves/SIMD: do NOT force
// min-waves in launch_bounds (round-7 lesson: forced (256,4) -> spill disaster).
__global__ __launch_bounds__(256, 2)
void attn_fwd(const bf16* __restrict__ Q, const bf16* __restrict__ KF,
              const bf16* __restrict__ VF, const int* __restrict__ mask,
              bf16* __restrict__ O) {
  const int lin = blockIdx.x;
  const int xcd = lin & 7, rest = lin >> 3;
  const int bh = xcd + 8 * (rest & 3);           // 4 heads per XCD -> K/V L2-resident
  const int job = rest >> 2;                     // 0..31
  const int b = bh >> 4, h = bh & 15;
  const int wq = threadIdx.x >> 6, lane = threadIdx.x & 63;
  const int l31 = lane & 31, hi = lane >> 5;

  __shared__ float accL[3][64][33];
  __shared__ float mlL[3][64][2];

  const size_t bqk = (size_t)b * 2048 * 1024 + h * 64;
  const size_t fbase = (size_t)bh * 131072;  // KF/VF per-head base

  for (int si = 0; si < 2; ++si) {
    const int s = si ? (63 - job) : job;   // strip: 32 q-rows
    const int q0 = 32 * s;
    const int T = (s >> 1) + 1;
    const int tstart = (T * wq) >> 2;
    const int tend = (T * (wq + 1)) >> 2;

    short8 qf[4];
#pragma unroll
    for (int s4 = 0; s4 < 4; ++s4)
      qf[s4] = *(const short8*)(Q + bqk + (size_t)(q0 + l31) * 1024 + 16 * s4 + 8 * hi);

    // once-per-range pad-mask scan (all-ones fast path)
    int anyz = 0;
    for (int i = tstart * 64 + lane; i < tend * 64; i += 64)
      anyz |= (mask[b * 2048 + i] == 0);
    const bool doMask = __any(anyz);

    f32x16 acc0 = {}, acc1 = {};
    float m = -1e30f, l = 0.f;

    short8 kf[2][4], kn[2][4], vf[2][4];
    if (tstart < tend) {
#pragma unroll
      for (int u = 0; u < 2; ++u)
#pragma unroll
        for (int s4 = 0; s4 < 4; ++s4)
          kf[u][s4] = *(const short8*)(KF + fbase +
              ((size_t)((2 * tstart + u) * 4 + s4) * 2 + hi) * 256 + l31 * 8);
    }

    for (int tt = tstart; tt < tend; ++tt) {
#pragma unroll
      for (int n = 0; n < 2; ++n)
#pragma unroll
        for (int tq = 0; tq < 4; ++tq)
          vf[n][tq] = *(const short8*)(VF + fbase +
              ((size_t)(((tt * 2 + n) * 4 + tq) * 2 + hi)) * 256 + l31 * 8);

      f32x16 s0 = {}, s1 = {};
      __builtin_amdgcn_s_setprio(1);
#pragma unroll
      for (int s4 = 0; s4 < 4; ++s4) {
        s0 = __builtin_amdgcn_mfma_f32_32x32x16_bf16(kf[0][s4], qf[s4], s0, 0, 0, 0);
        s1 = __builtin_amdgcn_mfma_f32_32x32x16_bf16(kf[1][s4], qf[s4], s1, 0, 0, 0);
      }
      __builtin_amdgcn_s_setprio(0);
      if (tt + 1 < tend) {  // K prefetch for next tile
#pragma unroll
        for (int u = 0; u < 2; ++u)
#pragma unroll
          for (int s4 = 0; s4 < 4; ++s4)
            kn[u][s4] = *(const short8*)(KF + fbase +
                ((size_t)((2 * (tt + 1) + u) * 4 + s4) * 2 + hi) * 256 + l31 * 8);
      }

      float w[2][16];
#pragma unroll
      for (int p = 0; p < 16; ++p) { w[0][p] = s0[p]; w[1][p] = s1[p]; }

      if (doMask) {  // pad-mask path (wave-uniform branch)
        int mv = mask[b * 2048 + tt * 64 + lane];
        uint64_t bits = __ballot(mv != 0);
        uint64_t bs = bits >> (4 * hi);
#pragma unroll
        for (int u = 0; u < 2; ++u)
#pragma unroll
          for (int p = 0; p < 16; ++p)
            if (!((bs >> (32 * u + (p & 3) + 8 * (p >> 2))) & 1)) w[u][p] = -3e38f;
      }
      if (tt == T - 1) {  // causal clamp, diagonal tile only (last quarter's last tile)
        int qr = 32 * (s & 1) + l31 - 4 * hi;
#pragma unroll
        for (int u = 0; u < 2; ++u)
#pragma unroll
          for (int p = 0; p < 16; ++p)
            if (32 * u + (p & 3) + 8 * (p >> 2) > qr) w[u][p] = -3e38f;
      }

      // tile max: v_max3 chain (16 ops) + one cross-half swap
      float tm = max3f(w[0][0], w[0][1], w[0][2]);
#pragma unroll
      for (int p = 3; p + 1 < 16; p += 2) tm = max3f(tm, w[0][p], w[0][p + 1]);
      tm = max3f(tm, w[0][15], w[1][0]);
#pragma unroll
      for (int p = 1; p + 1 < 16; p += 2) tm = max3f(tm, w[1][p], w[1][p + 1]);
      tm = fmaxf(tm, w[1][15]);
      tm = fmaxf(tm, __shfl_xor(tm, 32));

      // defer-max (T13)
      if (!__all(tm <= m + 8.f)) {
        float mn = fmaxf(m, tm);
        float corr = __builtin_amdgcn_exp2f(m - mn);
        m = mn; l *= corr;
#pragma unroll
        for (int p = 0; p < 16; ++p) {
          float ct = __shfl(corr, (p & 3) + 8 * (p >> 2) + 4 * hi);
          acc0[p] *= ct; acc1[p] *= ct;
        }
      }

      float ts = 0.f;
#pragma unroll
      for (int u = 0; u < 2; ++u)
#pragma unroll
        for (int p = 0; p < 16; ++p) {
          float pv = __builtin_amdgcn_exp2f(w[u][p] - m);
          w[u][p] = pv; ts += pv;
        }
      ts += __shfl_xor(ts, 32);
      l += ts;

      // pack P to bf16 pairs (T12)
      uint32_t pkk[2][8];
#pragma unroll
      for (int u = 0; u < 2; ++u)
#pragma unroll
        for (int a = 0; a < 4; ++a)
#pragma unroll
          for (int w2 = 0; w2 < 2; ++w2) {
            uint32_t r;
            asm("v_cvt_pk_bf16_f32 %0, %1, %2"
                : "=v"(r) : "v"(w[u][4 * a + 2 * w2]), "v"(w[u][4 * a + 2 * w2 + 1]));
            pkk[u][2 * a + w2] = r;
          }

      // PV A-frags via permlane32_swap, then 8 PV MFMAs
#pragma unroll
      for (int tq = 0; tq < 4; ++tq) {
        const int u = tq >> 1, alo = 2 * (tq & 1);
        uint32_t a0 = pkk[u][2 * alo + 0], b0 = pkk[u][2 * alo + 2];
        uint32_t a1 = pkk[u][2 * alo + 1], b1 = pkk[u][2 * alo + 3];
        asm("v_permlane32_swap_b32 %0, %1" : "+v"(a0), "+v"(b0));
        asm("v_permlane32_swap_b32 %0, %1" : "+v"(a1), "+v"(b1));
        u32x4 wv = {a0, a1, b0, b1};
        short8 paf = __builtin_bit_cast(short8, wv);
        __builtin_amdgcn_s_setprio(1);
        acc0 = __builtin_amdgcn_mfma_f32_32x32x16_bf16(paf, vf[0][tq], acc0, 0, 0, 0);
        acc1 = __builtin_amdgcn_mfma_f32_32x32x16_bf16(paf, vf[1][tq], acc1, 0, 0, 0);
        __builtin_amdgcn_s_setprio(0);
      }

#pragma unroll
      for (int u = 0; u < 2; ++u)
#pragma unroll
        for (int s4 = 0; s4 < 4; ++s4) kf[u][s4] = kn[u][s4];
    }

    // ---- 4-way split-K merge: waves 1..3 publish, wave 0 combines + writes ----
    if (wq) {
#pragma unroll
      for (int p = 0; p < 16; ++p) {
        accL[wq - 1][lane][p] = acc0[p];
        accL[wq - 1][lane][16 + p] = acc1[p];
      }
      mlL[wq - 1][lane][0] = m; mlL[wq - 1][lane][1] = l;
    }
    __syncthreads();
    if (wq == 0) {
      float ms = m;
#pragma unroll
      for (int j = 0; j < 3; ++j) ms = fmaxf(ms, mlL[j][lane][0]);
      float f0 = __builtin_amdgcn_exp2f(m - ms);
      float lsum = f0 * l;
      float fj[3];
#pragma unroll
      for (int j = 0; j < 3; ++j) {
        fj[j] = __builtin_amdgcn_exp2f(mlL[j][lane][0] - ms);
        lsum += fj[j] * mlL[j][lane][1];
      }
      float inv = 1.f / lsum;
      f0 *= inv;
#pragma unroll
      for (int j = 0; j < 3; ++j) fj[j] *= inv;
      unsigned short* Ou = (unsigned short*)O;
#pragma unroll
      for (int p = 0; p < 16; ++p) {
        int crow = (p & 3) + 8 * (p >> 2) + 4 * hi;
        float w0 = __shfl(f0, crow);
        float o0 = acc0[p] * w0, o1 = acc1[p] * w0;
#pragma unroll
        for (int j = 0; j < 3; ++j) {
          float wj = __shfl(fj[j], crow);
          o0 += accL[j][lane][p] * wj;
          o1 += accL[j][lane][16 + p] * wj;
        }
        size_t ro = (size_t)(b * 2048 + q0 + crow) * 1024 + h * 64;
        Ou[ro + l31] = f2b(o0);
        Ou[ro + 32 + l31] = f2b(o1);
      }
    }
    __syncthreads();
  }
}

// ---------------- launch ----------------
extern "C" void kernel_launch(void* const* d_in, const int* in_sizes, int n_in,
                              void* d_out, int out_size, void* d_ws, size_t ws_size,
                              hipStream_t stream) {
  const float* q = (const float*)d_in[0];
  const float* k = (const float*)d_in[1];
  const float* v = (const float*)d_in[2];
  const int* mask = (const int*)d_in[3];
  const float* Wq = (const float*)d_in[4];
  const float* Wk = (const float*)d_in[5];
  const float* Wv = (const float*)d_in[6];
  const float* Wo = (const float*)d_in[7];
  float* out = (float*)d_out;

  const size_t NT = 4096 * 1024;
  const size_t NW = 1024 * 1024;
  bf16* p = (bf16*)d_ws;
  bf16* qb = p;  p += NT;
  bf16* kb = p;  p += NT;
  bf16* vb = p;  p += NT;
  bf16* Wqb = p; p += NW;
  bf16* Wkb = p; p += NW;
  bf16* Wvb = p; p += NW;
  bf16* Wob = p; p += NW;
  bf16* Qh = p;  p += NT;
  bf16* KF = p;  p += NT;
  bf16* VF = p;  p += NT;
  bf16* Oh = p;  p += NT;

  cast_all<<<2048, 256, 0, stream>>>(q, k, v, Wq, Wk, Wv, Wo,
                                     qb, kb, vb, Wqb, Wkb, Wvb, Wob);
  qkv_proj<<<768, 256, 0, stream>>>(qb, kb, vb, Wqb, Wkb, Wvb, Qh, KF, VF);
  attn_fwd<<<1024, 256, 0, stream>>>(Qh, KF, VF, mask, Oh);
  gemm_o<<<512, 256, 0, stream>>>(Oh, Wob, out);
}